// Round 7
// baseline (658.752 us; speedup 1.0000x reference)
//
#include <hip/hip_runtime.h>

#define BB 256
#define NPER 512
#define FF 256
#define DD 32
#define EE 524288
#define NN (BB*NPER)          // 131072
#define NSTEPS 4

__device__ __forceinline__ float bflo(unsigned u) { return __uint_as_float(u << 16); }
__device__ __forceinline__ float bfhi(unsigned u) { return __uint_as_float(u & 0xFFFF0000u); }
__device__ __forceinline__ unsigned rtn_bf16(unsigned u) {
    return (u + 0x7FFFu + ((u >> 16) & 1u)) >> 16;
}

// ---------------- one-time kernels ----------------

__global__ void k_degpack(const int* __restrict__ dst, unsigned* __restrict__ deg,
                          const float* __restrict__ xs0, const float* __restrict__ q,
                          float2* __restrict__ xq) {
    int t = blockIdx.x * blockDim.x + threadIdx.x;
    if (t < NN) { float2 v; v.x = xs0[t]; v.y = q[t]; xq[t] = v; }
    atomicAdd(&deg[dst[t]], 1u);
}

__global__ void k_bsum(const unsigned* __restrict__ deg, unsigned* __restrict__ bsum) {
    __shared__ unsigned r[256];
    int t = threadIdx.x;
    r[t] = deg[blockIdx.x * 256 + t];
    __syncthreads();
    for (int o = 128; o > 0; o >>= 1) { if (t < o) r[t] += r[t + o]; __syncthreads(); }
    if (t == 0) bsum[blockIdx.x] = r[0];
}

__global__ void k_scanb(const unsigned* __restrict__ bsum, unsigned* __restrict__ bbase) {
    __shared__ unsigned r[512];
    int t = threadIdx.x;
    unsigned own = bsum[t];
    r[t] = own;
    __syncthreads();
    for (int o = 1; o < 512; o <<= 1) {
        unsigned v = (t >= o) ? r[t - o] : 0u;
        __syncthreads();
        r[t] += v;
        __syncthreads();
    }
    bbase[t] = r[t] - own;
}

__global__ void k_offsets(const unsigned* __restrict__ deg, const unsigned* __restrict__ bbase,
                          unsigned* __restrict__ rowstart, unsigned* __restrict__ cursor) {
    __shared__ unsigned r[256];
    int t = threadIdx.x;
    int i = blockIdx.x * 256 + t;
    unsigned d = deg[i];
    r[t] = d;
    __syncthreads();
    for (int o = 1; o < 256; o <<= 1) {
        unsigned v = (t >= o) ? r[t - o] : 0u;
        __syncthreads();
        r[t] += v;
        __syncthreads();
    }
    unsigned excl = r[t] - d + bbase[blockIdx.x];
    rowstart[i] = excl;
    cursor[i] = excl;
}

__global__ void k_fill(const int* __restrict__ src, const int* __restrict__ dst,
                       unsigned* __restrict__ cursor, int* __restrict__ csr_src) {
    int e = blockIdx.x * blockDim.x + threadIdx.x;
    unsigned pos = atomicAdd(&cursor[dst[e]], 1u);
    csr_src[pos] = src[e];
}

// init parity-0 accumulators: df=0, accs=0, alphaMin=+inf
__global__ void k_init(float* __restrict__ df0, float* __restrict__ accs0,
                       unsigned* __restrict__ alpha0) {
    int t = threadIdx.x;
    df0[blockIdx.x * 256 + t] = 0.f;
    if (t == 0) {
        accs0[blockIdx.x] = 0.f;
        accs0[BB + blockIdx.x] = 0.f;
        alpha0[blockIdx.x] = 0x7f800000u;
    }
}

// ---------------- per-step kernels ----------------

// fused gather + node MLP + per-graph |pred|,|r| partial sums
__global__ void k_node_g(const float2* __restrict__ xq, const float* __restrict__ xsol,
                         const float* __restrict__ Win, const float* __restrict__ bin,
                         const unsigned* __restrict__ rowstart, const unsigned* __restrict__ deg,
                         const int* __restrict__ csr_src,
                         const float* __restrict__ Wmsg, const float* __restrict__ bmsg,
                         const float* __restrict__ Wout, const float* __restrict__ bout,
                         float* __restrict__ pred, float* __restrict__ out_preds,
                         float* __restrict__ accsP, int step) {
    __shared__ float sp_[8], sr_[8];
    int tid = threadIdx.x;                  // 256 = 8 nodes x 32 channels
    int d = tid & 31;
    int ni = tid >> 5;
    int i = blockIdx.x * 8 + ni;
    int b = blockIdx.x >> 6;                // 64 blocks per graph
    float w0 = Win[d], w1 = Win[DD + d], b0 = bin[d];
    float wcol[DD];
    #pragma unroll
    for (int k = 0; k < DD; ++k) wcol[k] = Wmsg[k * DD + d];   // coalesced, L1-cached
    unsigned rs = rowstart[i];
    unsigned dg = deg[i];
    unsigned nfull = dg < 32u ? dg : 32u;
    float xv = 0.f, qv = 0.f;
    if ((unsigned)d < nfull) {
        int sv = csr_src[rs + d];            // coalesced across lanes
        float2 v = xq[sv];                   // single 8B gather per edge
        xv = v.x; qv = v.y;
    }
    float s = 0.f;
    for (unsigned j = 0; j < nfull; ++j) {
        float xj = __shfl(xv, (int)j, 32);
        float qj = __shfl(qv, (int)j, 32);
        s += fmaxf(xj * w0 + qj * w1 + b0, 0.f);
    }
    for (unsigned j = 32; j < dg; ++j) {     // rare tail (deg > 32)
        int sv = csr_src[rs + j];
        float2 v = xq[sv];
        s += fmaxf(v.x * w0 + v.y * w1 + b0, 0.f);
    }
    float2 self = xq[i];
    float hval = fmaxf(self.x * w0 + self.y * w1 + b0, 0.f);
    float agg = (float)dg * bmsg[d];
    #pragma unroll
    for (int k = 0; k < DD; ++k) agg += __shfl(s, k, 32) * wcol[k];
    float h2 = fmaxf(hval + agg, 0.f);
    float v = h2 * Wout[d];
    for (int o = 16; o > 0; o >>= 1) v += __shfl_down(v, o, 32);
    if (d == 0) {
        float pr = v + bout[0];
        pred[i] = pr;
        out_preds[i * NSTEPS + step] = pr;
        sp_[ni] = fabsf(pr);
        sr_[ni] = fabsf(xsol[i] - self.x);
    }
    __syncthreads();
    if (tid == 0) {
        float a = 0.f, c = 0.f;
        #pragma unroll
        for (int k = 0; k < 8; ++k) { a += sp_[k]; c += sr_[k]; }
        atomicAdd(&accsP[b], c);        // Sr
        atomicAdd(&accsP[BB + b], a);   // Sp
    }
}

// labels + dd-on-the-fly + df partial (atomic fold). 4 blocks/graph, 256 thr.
// Step 0 reads fp32 P and writes bf16 copy inline; later steps read bf16.
__global__ void k_df(const float* __restrict__ Pf, unsigned short* __restrict__ Pbf,
                     const float2* __restrict__ xq, const float* __restrict__ xsol,
                     const float* __restrict__ pred, float* __restrict__ out_labels,
                     const float* __restrict__ accsP, float* __restrict__ dfP,
                     float tau, int step) {
    __shared__ float ddl[128];
    __shared__ float sl[4 * FF];
    int b = blockIdx.x >> 2, sp = blockIdx.x & 3;
    int t = threadIdx.x, w = t >> 6, lane = t & 63;
    int nb = b * NPER + sp * 128;
    float Sr = accsP[b] + 1e-12f;
    float Sp = accsP[BB + b] + 1e-12f;
    if (t < 128) {
        int i = nb + t;
        float x = xq[i].x;
        float r = xsol[i] - x;
        out_labels[i * NSTEPS + step] = r / Sr;
        ddl[t] = pred[i] / Sp + 3.0f * tau / (x + tau);
    }
    __syncthreads();
    float4 acc = {0.f, 0.f, 0.f, 0.f};
    size_t rowbase = (size_t)(nb + w * 32) * FF;
    const float* dw = &ddl[w * 32];
    if (step == 0) {
        const float4* Pr = (const float4*)(Pf + rowbase) + lane;
        uint2* Pw = (uint2*)(Pbf + rowbase) + lane;
        #pragma unroll 4
        for (int n = 0; n < 32; ++n) {
            float4 pv = Pr[(size_t)n * 64];
            float sc = dw[n];
            acc.x += pv.x * sc; acc.y += pv.y * sc;
            acc.z += pv.z * sc; acc.w += pv.w * sc;
            unsigned u0 = rtn_bf16(__float_as_uint(pv.x));
            unsigned u1 = rtn_bf16(__float_as_uint(pv.y));
            unsigned u2 = rtn_bf16(__float_as_uint(pv.z));
            unsigned u3 = rtn_bf16(__float_as_uint(pv.w));
            uint2 o; o.x = u0 | (u1 << 16); o.y = u2 | (u3 << 16);
            Pw[(size_t)n * 64] = o;
        }
    } else {
        const uint2* Pr = (const uint2*)(Pbf + rowbase) + lane;
        #pragma unroll 8
        for (int n = 0; n < 32; ++n) {
            uint2 pv = Pr[(size_t)n * 64];
            float sc = dw[n];
            acc.x += bflo(pv.x) * sc; acc.y += bfhi(pv.x) * sc;
            acc.z += bflo(pv.y) * sc; acc.w += bfhi(pv.y) * sc;
        }
    }
    ((float4*)sl)[w * 64 + lane] = acc;      // sl[w*256 + feature]
    __syncthreads();
    float v = sl[t] + sl[FF + t] + sl[2 * FF + t] + sl[3 * FF + t];
    atomicAdd(&dfP[b * FF + t], v);          // 4 contributions/elem, L2-resident
}

// pproj + line-search partial min. 8 blocks/graph, 64 rows/block.
__global__ void k_pproj(const unsigned short* __restrict__ Pbf, const float* __restrict__ dfP,
                        const float2* __restrict__ xq,
                        float* __restrict__ pproj, unsigned* __restrict__ alphaP) {
    __shared__ float dfl[FF];
    __shared__ float mred[8];
    int t = threadIdx.x, g = t >> 5, l5 = t & 31;
    int b = blockIdx.x >> 3;
    dfl[t] = dfP[b * FF + t];
    __syncthreads();
    float4 dfa = ((const float4*)dfl)[l5 * 2];
    float4 dfb = ((const float4*)dfl)[l5 * 2 + 1];
    int n0 = blockIdx.x * 64 + g * 8;
    float m = 5.0f;
    #pragma unroll
    for (int it = 0; it < 8; ++it) {
        int n = n0 + it;
        uint4 pv = ((const uint4*)(Pbf + (size_t)n * FF))[l5];
        float a = bflo(pv.x) * dfa.x + bfhi(pv.x) * dfa.y
                + bflo(pv.y) * dfa.z + bfhi(pv.y) * dfa.w
                + bflo(pv.z) * dfb.x + bfhi(pv.z) * dfb.y
                + bflo(pv.w) * dfb.z + bfhi(pv.w) * dfb.w;
        #pragma unroll
        for (int o = 16; o > 0; o >>= 1) a += __shfl_down(a, o, 32);
        if (l5 == 0) {
            pproj[n] = a;
            float x = xq[n].x;
            float ratio = (a < 0.f) ? (x / fmaxf(-a, 1e-12f)) : 5.0f;
            m = fminf(m, ratio);
        }
    }
    if (l5 == 0) mred[g] = m;
    __syncthreads();
    if (t == 0) {
        float mm = mred[0];
        #pragma unroll
        for (int k = 1; k < 8; ++k) mm = fminf(mm, mred[k]);
        atomicMin(&alphaP[b], __float_as_uint(mm));
    }
}

// apply update; initialize next-parity accumulators (no races: double-buffered)
__global__ void k_upd(const unsigned* __restrict__ alphaP, const float* __restrict__ pproj,
                      float2* __restrict__ xq,
                      float* __restrict__ dfN, float* __restrict__ accsN,
                      unsigned* __restrict__ alphaN) {
    int t = threadIdx.x;
    int i = blockIdx.x * 256 + t;
    int b = i >> 9;
    float a = __uint_as_float(alphaP[b]);
    a = fminf(fmaxf(a, 0.f), 5.0f) * 0.995f;
    xq[i].x += a * pproj[i];
    if (t < 128) dfN[blockIdx.x * 128 + t] = 0.f;      // 512*128 = BB*FF
    else if (t == 128) accsN[blockIdx.x] = 0.f;        // 512 = 2*BB
    else if (t == 129 && blockIdx.x < BB) alphaN[blockIdx.x] = 0x7f800000u;
}

// last step: labels only
__global__ void k_labels(const float2* __restrict__ xq, const float* __restrict__ xsol,
                         const float* __restrict__ accsP, float* __restrict__ out_labels,
                         int step) {
    int i = blockIdx.x * 256 + threadIdx.x;
    int b = i >> 9;
    float Sr = accsP[b] + 1e-12f;
    out_labels[i * NSTEPS + step] = (xsol[i] - xq[i].x) / Sr;
}

// ---------------- launch ----------------

extern "C" void kernel_launch(void* const* d_in, const int* in_sizes, int n_in,
                              void* d_out, int out_size, void* d_ws, size_t ws_size,
                              hipStream_t stream) {
    const float* x_start = (const float*)d_in[0];
    const float* x_sol   = (const float*)d_in[1];
    const float* q       = (const float*)d_in[2];
    const float* P       = (const float*)d_in[3];
    const float* Win     = (const float*)d_in[4];
    const float* bin     = (const float*)d_in[5];
    const float* Wmsg    = (const float*)d_in[6];
    const float* bmsg    = (const float*)d_in[7];
    const float* Wout    = (const float*)d_in[8];
    const float* bout    = (const float*)d_in[9];
    const int*   esrc    = (const int*)d_in[10];
    const int*   edst    = (const int*)d_in[11];
    // d_in[12] vals_batch unused: batch(i) == i >> 9 (equal-sized contiguous graphs)

    float* out_preds  = (float*)d_out;                // [N, 4] row-major
    float* out_labels = (float*)d_out + (size_t)NN * NSTEPS;

    float* w = (float*)d_ws;
    float2* xq  = (float2*)w; w += 2 * (size_t)NN;
    float* pred  = w; w += NN;
    float* pproj = w; w += NN;
    float* df2   = w; w += 2 * (size_t)BB * FF;        // double-buffered df
    float* accs2 = w; w += 2 * 2 * BB;                 // [par][Sr(BB), Sp(BB)]
    unsigned* alpha2 = (unsigned*)w; w += 2 * BB;
    unsigned* deg      = (unsigned*)w; w += NN;
    unsigned* rowstart = (unsigned*)w; w += NN;
    unsigned* cursor   = (unsigned*)w; w += NN;
    unsigned* bsum     = (unsigned*)w; w += NN / 256;   // 512
    unsigned* bbase    = (unsigned*)w; w += NN / 256;   // 512
    int* csr_src       = (int*)w;      w += EE;
    unsigned short* Pbf = (unsigned short*)w;           // 64 MB bf16 copy of P

    // --- one-time: CSR build + xq pack + parity-0 accumulator init ---
    hipMemsetAsync(deg, 0, NN * sizeof(unsigned), stream);
    k_degpack<<<EE / 256, 256, 0, stream>>>(edst, deg, x_start, q, xq);
    k_init<<<BB, 256, 0, stream>>>(df2, accs2, alpha2);
    k_bsum<<<NN / 256, 256, 0, stream>>>(deg, bsum);
    k_scanb<<<1, NN / 256, 0, stream>>>(bsum, bbase);
    k_offsets<<<NN / 256, 256, 0, stream>>>(deg, bbase, rowstart, cursor);
    k_fill<<<EE / 256, 256, 0, stream>>>(esrc, edst, cursor, csr_src);

    float tau = 0.1f;
    for (int step = 0; step < NSTEPS; ++step) {
        int par = step & 1, np = par ^ 1;
        float* accsP = accs2 + par * 2 * BB;
        float* dfP   = df2 + (size_t)par * BB * FF;
        unsigned* alphaP = alpha2 + par * BB;
        k_node_g<<<NN / 8, 256, 0, stream>>>(xq, x_sol, Win, bin, rowstart, deg, csr_src,
                                             Wmsg, bmsg, Wout, bout, pred, out_preds,
                                             accsP, step);
        if (step < NSTEPS - 1) {
            k_df<<<BB * 4, 256, 0, stream>>>(P, Pbf, xq, x_sol, pred, out_labels,
                                             accsP, dfP, tau, step);
            k_pproj<<<NN / 64, 256, 0, stream>>>(Pbf, dfP, xq, pproj, alphaP);
            k_upd<<<NN / 256, 256, 0, stream>>>(alphaP, pproj, xq,
                                                df2 + (size_t)np * BB * FF,
                                                accs2 + np * 2 * BB, alpha2 + np * BB);
        } else {
            k_labels<<<NN / 256, 256, 0, stream>>>(xq, x_sol, accsP, out_labels, step);
        }
        tau = fmaxf(tau * 0.5f, 1e-5f);
    }
}

// Round 8
// 509.410 us; speedup vs baseline: 1.2932x; 1.2932x over previous
//
#include <hip/hip_runtime.h>

#define BB 256
#define NPER 512
#define FF 256
#define DD 32
#define EE 524288
#define NN (BB*NPER)          // 131072
#define NSTEPS 4

__device__ __forceinline__ float bflo(unsigned u) { return __uint_as_float(u << 16); }
__device__ __forceinline__ float bfhi(unsigned u) { return __uint_as_float(u & 0xFFFF0000u); }
__device__ __forceinline__ unsigned rtn_bf16(unsigned u) {
    return (u + 0x7FFFu + ((u >> 16) & 1u)) >> 16;
}

// ---------------- one-time kernels ----------------

__global__ void k_degpack(const int* __restrict__ dst, unsigned* __restrict__ deg,
                          const float* __restrict__ xs0, const float* __restrict__ q,
                          float2* __restrict__ xq) {
    int t = blockIdx.x * blockDim.x + threadIdx.x;
    if (t < NN) { float2 v; v.x = xs0[t]; v.y = q[t]; xq[t] = v; }
    atomicAdd(&deg[dst[t]], 1u);
}

__global__ void k_bsum(const unsigned* __restrict__ deg, unsigned* __restrict__ bsum) {
    __shared__ unsigned r[256];
    int t = threadIdx.x;
    r[t] = deg[blockIdx.x * 256 + t];
    __syncthreads();
    for (int o = 128; o > 0; o >>= 1) { if (t < o) r[t] += r[t + o]; __syncthreads(); }
    if (t == 0) bsum[blockIdx.x] = r[0];
}

__global__ void k_scanb(const unsigned* __restrict__ bsum, unsigned* __restrict__ bbase) {
    __shared__ unsigned r[512];
    int t = threadIdx.x;
    unsigned own = bsum[t];
    r[t] = own;
    __syncthreads();
    for (int o = 1; o < 512; o <<= 1) {
        unsigned v = (t >= o) ? r[t - o] : 0u;
        __syncthreads();
        r[t] += v;
        __syncthreads();
    }
    bbase[t] = r[t] - own;
}

__global__ void k_offsets(const unsigned* __restrict__ deg, const unsigned* __restrict__ bbase,
                          unsigned* __restrict__ rowstart, unsigned* __restrict__ cursor) {
    __shared__ unsigned r[256];
    int t = threadIdx.x;
    int i = blockIdx.x * 256 + t;
    unsigned d = deg[i];
    r[t] = d;
    __syncthreads();
    for (int o = 1; o < 256; o <<= 1) {
        unsigned v = (t >= o) ? r[t - o] : 0u;
        __syncthreads();
        r[t] += v;
        __syncthreads();
    }
    unsigned excl = r[t] - d + bbase[blockIdx.x];
    rowstart[i] = excl;
    cursor[i] = excl;
}

__global__ void k_fill(const int* __restrict__ src, const int* __restrict__ dst,
                       unsigned* __restrict__ cursor, int* __restrict__ csr_src) {
    int e = blockIdx.x * blockDim.x + threadIdx.x;
    unsigned pos = atomicAdd(&cursor[dst[e]], 1u);
    csr_src[pos] = src[e];
}

// ---------------- per-step kernels ----------------

// fused gather + node MLP (lean round-6 form; no reduction tail)
__global__ void k_node_g(const float2* __restrict__ xq,
                         const float* __restrict__ Win, const float* __restrict__ bin,
                         const unsigned* __restrict__ rowstart, const unsigned* __restrict__ deg,
                         const int* __restrict__ csr_src,
                         const float* __restrict__ Wmsg, const float* __restrict__ bmsg,
                         const float* __restrict__ Wout, const float* __restrict__ bout,
                         float* __restrict__ pred, float* __restrict__ out_preds, int step) {
    int tid = threadIdx.x;                  // 256 = 8 nodes x 32 channels
    int d = tid & 31;
    int i = blockIdx.x * 8 + (tid >> 5);
    float w0 = Win[d], w1 = Win[DD + d], b0 = bin[d];
    float wcol[DD];
    #pragma unroll
    for (int k = 0; k < DD; ++k) wcol[k] = Wmsg[k * DD + d];   // coalesced, L1-cached
    unsigned rs = rowstart[i];
    unsigned dg = deg[i];
    unsigned nfull = dg < 32u ? dg : 32u;
    float xv = 0.f, qv = 0.f;
    if ((unsigned)d < nfull) {
        int sv = csr_src[rs + d];            // coalesced across lanes
        float2 v = xq[sv];                   // single 8B gather per edge
        xv = v.x; qv = v.y;
    }
    float s = 0.f;
    for (unsigned j = 0; j < nfull; ++j) {
        float xj = __shfl(xv, (int)j, 32);
        float qj = __shfl(qv, (int)j, 32);
        s += fmaxf(xj * w0 + qj * w1 + b0, 0.f);
    }
    for (unsigned j = 32; j < dg; ++j) {     // rare tail (deg > 32)
        int sv = csr_src[rs + j];
        float2 v = xq[sv];
        s += fmaxf(v.x * w0 + v.y * w1 + b0, 0.f);
    }
    float2 self = xq[i];
    float hval = fmaxf(self.x * w0 + self.y * w1 + b0, 0.f);
    float agg = (float)dg * bmsg[d];
    #pragma unroll
    for (int k = 0; k < DD; ++k) agg += __shfl(s, k, 32) * wcol[k];
    float h2 = fmaxf(hval + agg, 0.f);
    float v = h2 * Wout[d];
    for (int o = 16; o > 0; o >>= 1) v += __shfl_down(v, o, 32);
    if (d == 0) {
        float pr = v + bout[0];
        pred[i] = pr;
        out_preds[i * NSTEPS + step] = pr;
    }
}

// mega per-graph kernel, 1024 threads (16 waves) per block for occupancy:
// labels + direction + df + pproj + line search + update. Step 0 reads fp32 P
// and writes the bf16 copy inline; later steps read bf16 (L3-resident).
__global__ __launch_bounds__(1024) void k_step(const float* __restrict__ Pf,
                                               unsigned short* __restrict__ Pbf,
                                               float2* __restrict__ xq,
                                               const float* __restrict__ xsol,
                                               const float* __restrict__ pred,
                                               float* __restrict__ out_labels,
                                               float tau, int step) {
    __shared__ float ddl[NPER];
    __shared__ float sl[16 * FF];
    __shared__ float dfl[FF];
    __shared__ float pp[NPER];
    __shared__ float red[16], red2[16];
    int b = blockIdx.x;
    int t = threadIdx.x;                 // 1024 = 16 waves
    int w = t >> 6, lane = t & 63;
    int i = b * NPER + (t & (NPER - 1));
    float x = 0.f, r = 0.f, p = 0.f;
    float a1 = 0.f, a2 = 0.f;
    if (t < NPER) {
        x = xq[i].x;
        r = xsol[i] - x;
        p = pred[i];
        a1 = fabsf(r); a2 = fabsf(p);
    }
    #pragma unroll
    for (int o = 32; o > 0; o >>= 1) {
        a1 += __shfl_down(a1, o, 64);
        a2 += __shfl_down(a2, o, 64);
    }
    if (lane == 0) { red[w] = a1; red2[w] = a2; }
    __syncthreads();
    float Sr = 1e-12f, Sp = 1e-12f;
    #pragma unroll
    for (int k = 0; k < 8; ++k) { Sr += red[k]; Sp += red2[k]; }
    if (t < NPER) out_labels[i * NSTEPS + step] = r / Sr;
    if (step == NSTEPS - 1) return;      // last-step projection/update is dead work
    if (t < NPER) ddl[t] = p / Sp + 3.0f * tau / (x + tau);
    __syncthreads();

    // --- df[f] = sum_n P[b,n,f]*dd[n]: wave w rows w*32..+31, lane = 4 features
    float4 acc = {0.f, 0.f, 0.f, 0.f};
    size_t rowbase = (size_t)(b * NPER + w * 32) * FF;
    const float* dw = &ddl[w * 32];
    if (step == 0) {
        const float4* Pr = (const float4*)(Pf + rowbase) + lane;
        uint2* Pw = (uint2*)(Pbf + rowbase) + lane;
        #pragma unroll 4
        for (int n = 0; n < 32; ++n) {
            float4 pv = Pr[(size_t)n * 64];
            float sc = dw[n];
            acc.x += pv.x * sc; acc.y += pv.y * sc;
            acc.z += pv.z * sc; acc.w += pv.w * sc;
            unsigned u0 = rtn_bf16(__float_as_uint(pv.x));
            unsigned u1 = rtn_bf16(__float_as_uint(pv.y));
            unsigned u2 = rtn_bf16(__float_as_uint(pv.z));
            unsigned u3 = rtn_bf16(__float_as_uint(pv.w));
            uint2 o; o.x = u0 | (u1 << 16); o.y = u2 | (u3 << 16);
            Pw[(size_t)n * 64] = o;
        }
    } else {
        const uint2* Pr = (const uint2*)(Pbf + rowbase) + lane;
        #pragma unroll 8
        for (int n = 0; n < 32; ++n) {
            uint2 pv = Pr[(size_t)n * 64];
            float sc = dw[n];
            acc.x += bflo(pv.x) * sc; acc.y += bfhi(pv.x) * sc;
            acc.z += bflo(pv.y) * sc; acc.w += bfhi(pv.y) * sc;
        }
    }
    ((float4*)sl)[w * 64 + lane] = acc;
    __syncthreads();
    if (t < FF) {
        float v = 0.f;
        #pragma unroll
        for (int k = 0; k < 16; ++k) v += sl[k * FF + t];
        dfl[t] = v;
    }
    __syncthreads();

    // --- pproj[n] = P[b,n,:].df : 32 groups of 32 lanes, 16 rows each
    int g = t >> 5, l5 = t & 31;
    float4 dfa = ((const float4*)dfl)[l5 * 2];
    float4 dfb = ((const float4*)dfl)[l5 * 2 + 1];
    const uint4* Pr4 = (const uint4*)(Pbf + (size_t)(b * NPER + g * 16) * FF) + l5;
    #pragma unroll 4
    for (int it = 0; it < 16; ++it) {
        uint4 pv = Pr4[(size_t)it * 32];
        float a = bflo(pv.x) * dfa.x + bfhi(pv.x) * dfa.y
                + bflo(pv.y) * dfa.z + bfhi(pv.y) * dfa.w
                + bflo(pv.z) * dfb.x + bfhi(pv.z) * dfb.y
                + bflo(pv.w) * dfb.z + bfhi(pv.w) * dfb.w;
        #pragma unroll
        for (int o = 16; o > 0; o >>= 1) a += __shfl_down(a, o, 32);
        if (l5 == 0) pp[g * 16 + it] = a;
    }
    __syncthreads();

    // --- line search + update (block-local, no atomics)
    float d = 0.f, m = 5.0f;
    if (t < NPER) {
        d = pp[t];
        m = (d < 0.f) ? (x / fmaxf(-d, 1e-12f)) : 5.0f;
    }
    #pragma unroll
    for (int o = 32; o > 0; o >>= 1) m = fminf(m, __shfl_down(m, o, 64));
    if (lane == 0) red[w] = m;
    __syncthreads();
    float mm = red[0];
    #pragma unroll
    for (int k = 1; k < 16; ++k) mm = fminf(mm, red[k]);
    float alpha = fminf(fmaxf(mm, 0.f), 5.0f) * 0.995f;
    if (t < NPER) xq[i].x = x + alpha * d;
}

// ---------------- launch ----------------

extern "C" void kernel_launch(void* const* d_in, const int* in_sizes, int n_in,
                              void* d_out, int out_size, void* d_ws, size_t ws_size,
                              hipStream_t stream) {
    const float* x_start = (const float*)d_in[0];
    const float* x_sol   = (const float*)d_in[1];
    const float* q       = (const float*)d_in[2];
    const float* P       = (const float*)d_in[3];
    const float* Win     = (const float*)d_in[4];
    const float* bin     = (const float*)d_in[5];
    const float* Wmsg    = (const float*)d_in[6];
    const float* bmsg    = (const float*)d_in[7];
    const float* Wout    = (const float*)d_in[8];
    const float* bout    = (const float*)d_in[9];
    const int*   esrc    = (const int*)d_in[10];
    const int*   edst    = (const int*)d_in[11];
    // d_in[12] vals_batch unused: batch(i) == i >> 9 (equal-sized contiguous graphs)

    float* out_preds  = (float*)d_out;                // [N, 4] row-major
    float* out_labels = (float*)d_out + (size_t)NN * NSTEPS;

    float* w = (float*)d_ws;
    float2* xq  = (float2*)w; w += 2 * (size_t)NN;
    float* pred  = w; w += NN;
    unsigned* deg      = (unsigned*)w; w += NN;
    unsigned* rowstart = (unsigned*)w; w += NN;
    unsigned* cursor   = (unsigned*)w; w += NN;
    unsigned* bsum     = (unsigned*)w; w += NN / 256;   // 512
    unsigned* bbase    = (unsigned*)w; w += NN / 256;   // 512
    int* csr_src       = (int*)w;      w += EE;
    unsigned short* Pbf = (unsigned short*)w;           // 64 MB bf16 copy of P

    // --- one-time: CSR build + xq pack (bf16 P cast fused into step-0 k_step)
    hipMemsetAsync(deg, 0, NN * sizeof(unsigned), stream);
    k_degpack<<<EE / 256, 256, 0, stream>>>(edst, deg, x_start, q, xq);
    k_bsum<<<NN / 256, 256, 0, stream>>>(deg, bsum);
    k_scanb<<<1, NN / 256, 0, stream>>>(bsum, bbase);
    k_offsets<<<NN / 256, 256, 0, stream>>>(deg, bbase, rowstart, cursor);
    k_fill<<<EE / 256, 256, 0, stream>>>(esrc, edst, cursor, csr_src);

    float tau = 0.1f;
    for (int step = 0; step < NSTEPS; ++step) {
        k_node_g<<<NN / 8, 256, 0, stream>>>(xq, Win, bin, rowstart, deg, csr_src,
                                             Wmsg, bmsg, Wout, bout, pred, out_preds, step);
        k_step<<<BB, 1024, 0, stream>>>(P, Pbf, xq, x_sol, pred, out_labels, tau, step);
        tau = fmaxf(tau * 0.5f, 1e-5f);
    }
}